// Round 7
// baseline (2801.308 us; speedup 1.0000x reference)
//
#include <hip/hip_runtime.h>

typedef __attribute__((ext_vector_type(8))) short short8;
typedef __attribute__((ext_vector_type(4))) float f32x4;

#define B_    8
#define CI    256
#define CO    256
#define Hh    160
#define Ww    160
#define HP    162
#define WP    162
#define HWp   (Hh * Ww)                 // 25600
#define XPAD_ELEMS (B_ * HP * WP * CI)  // 53,747,712 bf16
#define W3_ELEMS   (9 * CI * CO)        // 589,824 bf16 (granule order)
#define NT    36                        // 4 ci-chunks x 9 shifts, BK=64
#define BSLOT 8192                      // shorts per B slot: 128px x 64ci = 16KB

__device__ __forceinline__ unsigned short f2bf(float f) {
  unsigned int u = __float_as_uint(f);
  u += 0x7FFFu + ((u >> 16) & 1u);   // RNE
  return (unsigned short)(u >> 16);
}

// weight [co][ci][3][3] f32 -> w3 granules (same as r6):
// g = shift*128 + cic*32 + qm*16 + kk*8 + wm*2 + mi ; elem = g*512 + l*8 + e
// co = qm*128 + wm*32 + mi*16 + (l&15) ; ci = cic*64 + kk*32 + (l>>4)*8 + e
__global__ void prep_w_kernel(const float* __restrict__ w, unsigned short* __restrict__ w3) {
  int i = blockIdx.x * 256 + threadIdx.x;
  if (i >= W3_ELEMS) return;
  int e = i & 7, l = (i >> 3) & 63, g = i >> 9;
  int mi = g & 1, wm = (g >> 1) & 3, kk = (g >> 3) & 1;
  int qm = (g >> 4) & 1, cic = (g >> 5) & 3, shift = g >> 7;
  int co = qm * 128 + wm * 32 + mi * 16 + (l & 15);
  int ci = cic * 64 + kk * 32 + (l >> 4) * 8 + e;
  w3[i] = f2bf(w[(co * 256 + ci) * 9 + shift]);
}

// zero the padded border of xp
__global__ void zero_border(unsigned short* __restrict__ xp) {
  int g = blockIdx.x * 256 + threadIdx.x;
  int pos = g >> 5;
  int c = (g & 31) << 3;
  int n = pos / 644;
  int p = pos - n * 644;
  int y, x;
  if (p < 324) { y = (p < 162) ? 0 : 161; x = (p < 162) ? p : p - 162; }
  else { int q = p - 324; y = 1 + (q >> 1); x = (q & 1) ? 161 : 0; }
  unsigned short* d = xp + (((size_t)(n * 162 + y)) * 162 + x) * 256 + c;
  *(uint4*)d = (uint4){0u, 0u, 0u, 0u};
}

// ori [n][ci][h][w] f32 * mask -> xp [n][h+1][w+1][ci] bf16 (padded NHWC)
__global__ void prep_x_kernel(const float* __restrict__ ori, const int* __restrict__ mask,
                              unsigned short* __restrict__ xp) {
  int bid = blockIdx.x;                 // ((n*160+h)*4+cit)*3+wt
  int wt = bid % 3;
  int t1 = bid / 3;
  int cit = t1 & 3;
  int t2 = t1 >> 2;
  int h = t2 % Hh;
  int n = t2 / Hh;
  int t = threadIdx.x;

  __shared__ float tile[64][65];

  int wl = t & 63;
  int w = wt * 64 + wl;
  bool valid = (w < Ww);
  float m = 0.f;
  if (valid) m = (float)mask[(n * Hh + h) * Ww + w];
  const float* src = ori + (((size_t)(n * CI + cit * 64) * Hh + h) * Ww + w);
  int r0 = t >> 6;
#pragma unroll
  for (int k = 0; k < 16; ++k) {
    int ci_l = r0 * 16 + k;
    float v = 0.f;
    if (valid) v = src[(size_t)ci_l * HWp] * m;
    tile[ci_l][wl] = v;
  }
  __syncthreads();

  int wl2 = t >> 2;
  int wo = wt * 64 + wl2;
  if (wo < Ww) {
    int cseg = (t & 3) * 16;
    union { unsigned short u[8]; uint4 v; } p0, p1;
#pragma unroll
    for (int j = 0; j < 8; ++j) p0.u[j] = f2bf(tile[cseg + j][wl2]);
#pragma unroll
    for (int j = 0; j < 8; ++j) p1.u[j] = f2bf(tile[cseg + 8 + j][wl2]);
    unsigned short* dst = xp + ((size_t)((n * HP + h + 1) * WP) + (wo + 1)) * CI + cit * 64 + cseg;
    *(uint4*)dst = p0.v;
    *(uint4*)(dst + 8) = p1.v;
  }
}

__device__ __forceinline__ void gload16(const unsigned short* g, unsigned short* l) {
  __builtin_amdgcn_global_load_lds((const __attribute__((address_space(1))) void*)g,
                                   (__attribute__((address_space(3))) void*)l, 16, 0, 0);
}

// Implicit GEMM: A(weights) reg-pipelined from w3 (L2-hot), B(pixels) in 3-slot LDS ring.
// Block 256co x 128px, 256 thr = 4 waves; per-wave m: qm(2)xmi(2) frags, n: 8 frags.
// acc[2][2][8] f32x4. Per K-tile: STAGE(t+2)+AG(t+1) issued first, 16 B ds_reads,
// 2x32 MFMA clusters, then ONE s_waitcnt vmcnt(12) + ONE s_barrier.
// LDS 48KB -> 3 blocks/CU (desynced coverage). Grid 1600, image-per-XCD.
__global__ void __launch_bounds__(256, 3)
sconv_gemm(const unsigned short* __restrict__ xp, const unsigned short* __restrict__ w3,
           const float* __restrict__ bias, float* __restrict__ out) {
  __shared__ unsigned short Bs[3][BSLOT];   // 48KB

  const int bid = blockIdx.x;
  const int n = bid & 7;          // image per XCD (1600 = 8 x 200)
  const int pxt = bid >> 3;       // 0..199
  const int p0 = pxt * 128;       // first pixel (within image)

  const int t = threadIdx.x;
  const int l = t & 63;
  const int wv = t >> 6;

  const int lr = l >> 3;
  const int swz8 = ((l & 7) ^ lr) << 3;   // proven source pre-swizzle (shorts)
  const int lc = l & 15, hi4 = l >> 4, lx7 = l & 7;

  // B staging: wave wv covers px rows [wv*32, wv*32+32), granule g = 8 rows
  unsigned boff[4];
#pragma unroll
  for (int g = 0; g < 4; ++g) {
    int p = p0 + wv * 32 + g * 8 + lr;
    int h = p / Ww;
    int w = p - h * Ww;
    boff[g] = (unsigned)((n * HP + h) * WP + w) * 256 + swz8;
  }

  f32x4 acc[2][2][8];
#pragma unroll
  for (int a = 0; a < 2; ++a)
#pragma unroll
    for (int b = 0; b < 2; ++b)
#pragma unroll
      for (int c = 0; c < 8; ++c)
        acc[a][b][c] = (f32x4){0.f, 0.f, 0.f, 0.f};

  auto STAGE = [&](int ts, unsigned short* slot) {
    int cic = (ts * 57) >> 9;            // ts/9
    int sh = ts - cic * 9;
    int kh = (sh * 11) >> 5;             // sh/3
    int kw = sh - kh * 3;
    const unsigned short* src = xp + (unsigned)(kh * WP + kw) * 256 + (cic << 6);
    unsigned short* dst = slot + wv * 2048;
#pragma unroll
    for (int g = 0; g < 4; ++g)
      gload16(src + boff[g], dst + g * 512);
  };

  // A granules -> a[qm*4 + kk*2 + mi]
  auto AG = [&](int ts, short8* a) {
    int cic = (ts * 57) >> 9;
    int sh = ts - cic * 9;
    const unsigned short* p = w3 + (((unsigned)(sh * 128 + cic * 32 + wv * 2)) << 9) + (l << 3);
    a[0] = *(const short8*)(p);
    a[1] = *(const short8*)(p + 512);
    a[2] = *(const short8*)(p + 4096);
    a[3] = *(const short8*)(p + 4096 + 512);
    a[4] = *(const short8*)(p + 8192);
    a[5] = *(const short8*)(p + 8192 + 512);
    a[6] = *(const short8*)(p + 8192 + 4096);
    a[7] = *(const short8*)(p + 8192 + 4096 + 512);
  };

#define BBL(dst, slot, kk) do {                                               \
  _Pragma("unroll")                                                           \
  for (int ni = 0; ni < 8; ++ni)                                              \
    dst[ni] = *(const short8*)((slot) + (ni * 16 + lc) * 64 +                 \
                               (((((kk) << 2) + hi4) ^ lx7) << 3));           \
} while (0)

#define CLUSTER(bb, A, kk) do {                                               \
  __builtin_amdgcn_s_setprio(1);                                              \
  _Pragma("unroll")                                                           \
  for (int qm = 0; qm < 2; ++qm)                                              \
    _Pragma("unroll")                                                         \
    for (int mi = 0; mi < 2; ++mi)                                            \
      _Pragma("unroll")                                                       \
      for (int ni = 0; ni < 8; ++ni)                                          \
        acc[qm][mi][ni] = __builtin_amdgcn_mfma_f32_16x16x32_bf16(            \
            A[qm * 4 + (kk) * 2 + mi], bb[ni], acc[qm][mi][ni], 0, 0, 0);     \
  __builtin_amdgcn_s_setprio(0);                                              \
} while (0)

  unsigned short *s0 = &Bs[0][0], *s1 = &Bs[1][0], *s2 = &Bs[2][0];
  short8 aA[8], aB[8], bb0[8], bb1[8];

  // prologue
  STAGE(0, s0);
  STAGE(1, s1);
  AG(0, aA);
  asm volatile("s_waitcnt vmcnt(0)" ::: "memory");
  __builtin_amdgcn_s_barrier();

  // main loop: tiles 0..33 (17 x 2), tiles 34,35 peeled
  for (int tt = 0; tt < 34; tt += 2) {
    // ---- tile tt (A = aA) ----
    STAGE(tt + 2, s2);                 // 4 gload_lds (2-tile lead)
    AG(tt + 1, aB);                    // 8 global->reg (1-tile lead)
    BBL(bb0, s0, 0);
    BBL(bb1, s0, 1);
    CLUSTER(bb0, aA, 0);
    CLUSTER(bb1, aA, 1);
    asm volatile("s_waitcnt vmcnt(12)" ::: "memory");   // stage(tt+1) landed; 12 newest fly
    __builtin_amdgcn_s_barrier();
    { unsigned short* c = s0; s0 = s1; s1 = s2; s2 = c; }
    // ---- tile tt+1 (A = aB) ----
    STAGE(tt + 3, s2);                 // tt+3 <= 35 always
    AG(tt + 2, aA);
    BBL(bb0, s0, 0);
    BBL(bb1, s0, 1);
    CLUSTER(bb0, aB, 0);
    CLUSTER(bb1, aB, 1);
    asm volatile("s_waitcnt vmcnt(12)" ::: "memory");
    __builtin_amdgcn_s_barrier();
    { unsigned short* c = s0; s0 = s1; s1 = s2; s2 = c; }
  }

  // ---- tile 34 (A = aA) ----
  AG(35, aB);
  BBL(bb0, s0, 0);
  BBL(bb1, s0, 1);
  CLUSTER(bb0, aA, 0);
  CLUSTER(bb1, aA, 1);
  asm volatile("s_waitcnt vmcnt(8)" ::: "memory");      // forces stage(35) done
  __builtin_amdgcn_s_barrier();
  { unsigned short* c = s0; s0 = s1; s1 = s2; s2 = c; }
  // ---- tile 35 (A = aB) ----
  BBL(bb0, s0, 0);
  BBL(bb1, s0, 1);
  CLUSTER(bb0, aB, 0);
  CLUSTER(bb1, aB, 1);

  // epilogue: D col(px)=l&15, row(co)=(l>>4)*4+r
#pragma unroll
  for (int qm = 0; qm < 2; ++qm)
#pragma unroll
    for (int mi = 0; mi < 2; ++mi) {
      int cobase = qm * 128 + wv * 32 + mi * 16 + hi4 * 4;
      const float4 bv = *(const float4*)(bias + cobase);
#pragma unroll
      for (int ni = 0; ni < 8; ++ni) {
        int p = p0 + ni * 16 + lc;
        float* op = out + ((size_t)n * CO + cobase) * HWp + p;
        f32x4 v = acc[qm][mi][ni];
        op[0]               = v[0] + bv.x;
        op[(size_t)HWp]     = v[1] + bv.y;
        op[(size_t)2 * HWp] = v[2] + bv.z;
        op[(size_t)3 * HWp] = v[3] + bv.w;
      }
    }
}

extern "C" void kernel_launch(void* const* d_in, const int* in_sizes, int n_in,
                              void* d_out, int out_size, void* d_ws, size_t ws_size,
                              hipStream_t stream) {
  const int* mask = (const int*)d_in[0];
  const float* ori = (const float*)d_in[1];
  const float* weight = (const float*)d_in[2];
  const float* bias = (const float*)d_in[3];
  float* out = (float*)d_out;

  unsigned short* xp = (unsigned short*)d_ws;          // padded NHWC bf16, 107.5 MB
  unsigned short* w3 = xp + XPAD_ELEMS;                // 1.2 MB granule-ordered weights

  zero_border<<<644, 256, 0, stream>>>(xp);
  prep_w_kernel<<<(W3_ELEMS + 255) / 256, 256, 0, stream>>>(weight, w3);
  prep_x_kernel<<<B_ * Hh * 4 * 3, 256, 0, stream>>>(ori, mask, xp);
  sconv_gemm<<<1600, 256, 0, stream>>>(xp, w3, bias, out);
}

// Round 8
// 512.319 us; speedup vs baseline: 5.4679x; 5.4679x over previous
//
#include <hip/hip_runtime.h>

typedef __attribute__((ext_vector_type(8))) short short8;
typedef __attribute__((ext_vector_type(4))) float f32x4;

#define B_    8
#define CI    256
#define CO    256
#define Hh    160
#define Ww    160
#define HP    162
#define WP    162
#define HWp   (Hh * Ww)                 // 25600
#define XPAD_ELEMS (B_ * HP * WP * CI)  // 53,747,712 bf16
#define W3_ELEMS   (9 * CI * CO)        // 589,824 bf16 (granule order)
#define NT    36                        // 4 ci-chunks x 9 shifts, BK=64
#define BSLOT 8192                      // shorts per B slot: 128px x 64ci = 16KB

__device__ __forceinline__ unsigned short f2bf(float f) {
  unsigned int u = __float_as_uint(f);
  u += 0x7FFFu + ((u >> 16) & 1u);   // RNE
  return (unsigned short)(u >> 16);
}

// weight [co][ci][3][3] f32 -> w3 granules (same as r6/r7):
// g = shift*128 + cic*32 + qm*16 + kk*8 + wm*2 + mi ; elem = g*512 + l*8 + e
// co = qm*128 + wm*32 + mi*16 + (l&15) ; ci = cic*64 + kk*32 + (l>>4)*8 + e
__global__ void prep_w_kernel(const float* __restrict__ w, unsigned short* __restrict__ w3) {
  int i = blockIdx.x * 256 + threadIdx.x;
  if (i >= W3_ELEMS) return;
  int e = i & 7, l = (i >> 3) & 63, g = i >> 9;
  int mi = g & 1, wm = (g >> 1) & 3, kk = (g >> 3) & 1;
  int qm = (g >> 4) & 1, cic = (g >> 5) & 3, shift = g >> 7;
  int co = qm * 128 + wm * 32 + mi * 16 + (l & 15);
  int ci = cic * 64 + kk * 32 + (l >> 4) * 8 + e;
  w3[i] = f2bf(w[(co * 256 + ci) * 9 + shift]);
}

// zero the padded border of xp
__global__ void zero_border(unsigned short* __restrict__ xp) {
  int g = blockIdx.x * 256 + threadIdx.x;
  int pos = g >> 5;
  int c = (g & 31) << 3;
  int n = pos / 644;
  int p = pos - n * 644;
  int y, x;
  if (p < 324) { y = (p < 162) ? 0 : 161; x = (p < 162) ? p : p - 162; }
  else { int q = p - 324; y = 1 + (q >> 1); x = (q & 1) ? 161 : 0; }
  unsigned short* d = xp + (((size_t)(n * 162 + y)) * 162 + x) * 256 + c;
  *(uint4*)d = (uint4){0u, 0u, 0u, 0u};
}

// ori [n][ci][h][w] f32 * mask -> xp [n][h+1][w+1][ci] bf16 (padded NHWC)
__global__ void prep_x_kernel(const float* __restrict__ ori, const int* __restrict__ mask,
                              unsigned short* __restrict__ xp) {
  int bid = blockIdx.x;                 // ((n*160+h)*4+cit)*3+wt
  int wt = bid % 3;
  int t1 = bid / 3;
  int cit = t1 & 3;
  int t2 = t1 >> 2;
  int h = t2 % Hh;
  int n = t2 / Hh;
  int t = threadIdx.x;

  __shared__ float tile[64][65];

  int wl = t & 63;
  int w = wt * 64 + wl;
  bool valid = (w < Ww);
  float m = 0.f;
  if (valid) m = (float)mask[(n * Hh + h) * Ww + w];
  const float* src = ori + (((size_t)(n * CI + cit * 64) * Hh + h) * Ww + w);
  int r0 = t >> 6;
#pragma unroll
  for (int k = 0; k < 16; ++k) {
    int ci_l = r0 * 16 + k;
    float v = 0.f;
    if (valid) v = src[(size_t)ci_l * HWp] * m;
    tile[ci_l][wl] = v;
  }
  __syncthreads();

  int wl2 = t >> 2;
  int wo = wt * 64 + wl2;
  if (wo < Ww) {
    int cseg = (t & 3) * 16;
    union { unsigned short u[8]; uint4 v; } p0, p1;
#pragma unroll
    for (int j = 0; j < 8; ++j) p0.u[j] = f2bf(tile[cseg + j][wl2]);
#pragma unroll
    for (int j = 0; j < 8; ++j) p1.u[j] = f2bf(tile[cseg + 8 + j][wl2]);
    unsigned short* dst = xp + ((size_t)((n * HP + h + 1) * WP) + (wo + 1)) * CI + cit * 64 + cseg;
    *(uint4*)dst = p0.v;
    *(uint4*)(dst + 8) = p1.v;
  }
}

__device__ __forceinline__ void gload16(const unsigned short* g, unsigned short* l) {
  __builtin_amdgcn_global_load_lds((const __attribute__((address_space(1))) void*)g,
                                   (__attribute__((address_space(3))) void*)l, 16, 0, 0);
}

// Implicit GEMM: A(weights) reg-pipelined from w3 (L2-hot), B(pixels) in 3-slot LDS ring.
// Block 256co x 128px, 256 thr = 4 waves; per-wave m: qm(2)xmi(2) frags, n: 8 frags.
// acc[2][2][8] f32x4. Per K-tile: STAGE(t+2)+AG(t+1) issued first, 16 B ds_reads,
// 2x32 MFMA clusters, then ONE s_waitcnt vmcnt(12) + ONE s_barrier.
// __launch_bounds__(256,2): 2 blocks/CU, 256-reg budget (r7's (256,3) capped at 170
// and spilled acc to scratch -> 7.4GB HBM writes; this is the fix).
__global__ void __launch_bounds__(256, 2)
sconv_gemm(const unsigned short* __restrict__ xp, const unsigned short* __restrict__ w3,
           const float* __restrict__ bias, float* __restrict__ out) {
  __shared__ unsigned short Bs[3][BSLOT];   // 48KB

  const int bid = blockIdx.x;
  const int n = bid & 7;          // image per XCD (1600 = 8 x 200)
  const int pxt = bid >> 3;       // 0..199
  const int p0 = pxt * 128;       // first pixel (within image)

  const int t = threadIdx.x;
  const int l = t & 63;
  const int wv = t >> 6;

  const int lr = l >> 3;
  const int swz8 = ((l & 7) ^ lr) << 3;   // proven source pre-swizzle (shorts)
  const int lc = l & 15, hi4 = l >> 4, lx7 = l & 7;

  // B staging: wave wv covers px rows [wv*32, wv*32+32), granule g = 8 rows
  unsigned boff[4];
#pragma unroll
  for (int g = 0; g < 4; ++g) {
    int p = p0 + wv * 32 + g * 8 + lr;
    int h = p / Ww;
    int w = p - h * Ww;
    boff[g] = (unsigned)((n * HP + h) * WP + w) * 256 + swz8;
  }

  f32x4 acc[2][2][8];
#pragma unroll
  for (int a = 0; a < 2; ++a)
#pragma unroll
    for (int b = 0; b < 2; ++b)
#pragma unroll
      for (int c = 0; c < 8; ++c)
        acc[a][b][c] = (f32x4){0.f, 0.f, 0.f, 0.f};

  auto STAGE = [&](int ts, unsigned short* slot) {
    int cic = (ts * 57) >> 9;            // ts/9
    int sh = ts - cic * 9;
    int kh = (sh * 11) >> 5;             // sh/3
    int kw = sh - kh * 3;
    const unsigned short* src = xp + (unsigned)(kh * WP + kw) * 256 + (cic << 6);
    unsigned short* dst = slot + wv * 2048;
#pragma unroll
    for (int g = 0; g < 4; ++g)
      gload16(src + boff[g], dst + g * 512);
  };

  // A granules -> a[qm*4 + kk*2 + mi]
  auto AG = [&](int ts, short8* a) {
    int cic = (ts * 57) >> 9;
    int sh = ts - cic * 9;
    const unsigned short* p = w3 + (((unsigned)(sh * 128 + cic * 32 + wv * 2)) << 9) + (l << 3);
    a[0] = *(const short8*)(p);
    a[1] = *(const short8*)(p + 512);
    a[2] = *(const short8*)(p + 4096);
    a[3] = *(const short8*)(p + 4096 + 512);
    a[4] = *(const short8*)(p + 8192);
    a[5] = *(const short8*)(p + 8192 + 512);
    a[6] = *(const short8*)(p + 8192 + 4096);
    a[7] = *(const short8*)(p + 8192 + 4096 + 512);
  };

#define BBL(dst, slot, kk) do {                                               \
  _Pragma("unroll")                                                           \
  for (int ni = 0; ni < 8; ++ni)                                              \
    dst[ni] = *(const short8*)((slot) + (ni * 16 + lc) * 64 +                 \
                               (((((kk) << 2) + hi4) ^ lx7) << 3));           \
} while (0)

#define CLUSTER(bb, A, kk) do {                                               \
  __builtin_amdgcn_s_setprio(1);                                              \
  _Pragma("unroll")                                                           \
  for (int qm = 0; qm < 2; ++qm)                                              \
    _Pragma("unroll")                                                         \
    for (int mi = 0; mi < 2; ++mi)                                            \
      _Pragma("unroll")                                                       \
      for (int ni = 0; ni < 8; ++ni)                                          \
        acc[qm][mi][ni] = __builtin_amdgcn_mfma_f32_16x16x32_bf16(            \
            A[qm * 4 + (kk) * 2 + mi], bb[ni], acc[qm][mi][ni], 0, 0, 0);     \
  __builtin_amdgcn_s_setprio(0);                                              \
} while (0)

  unsigned short *s0 = &Bs[0][0], *s1 = &Bs[1][0], *s2 = &Bs[2][0];
  short8 aA[8], aB[8], bb0[8], bb1[8];

  // prologue
  STAGE(0, s0);
  STAGE(1, s1);
  AG(0, aA);
  asm volatile("s_waitcnt vmcnt(0)" ::: "memory");
  __builtin_amdgcn_s_barrier();

  // main loop: tiles 0..33 (17 x 2), tiles 34,35 peeled
  for (int tt = 0; tt < 34; tt += 2) {
    // ---- tile tt (A = aA) ----
    STAGE(tt + 2, s2);                 // 4 gload_lds (2-tile lead)
    AG(tt + 1, aB);                    // 8 global->reg (1-tile lead)
    BBL(bb0, s0, 0);
    BBL(bb1, s0, 1);
    CLUSTER(bb0, aA, 0);
    CLUSTER(bb1, aA, 1);
    asm volatile("s_waitcnt vmcnt(12)" ::: "memory");   // stage(tt+1) landed; 12 newest fly
    __builtin_amdgcn_s_barrier();
    { unsigned short* c = s0; s0 = s1; s1 = s2; s2 = c; }
    // ---- tile tt+1 (A = aB) ----
    STAGE(tt + 3, s2);                 // tt+3 <= 35 always
    AG(tt + 2, aA);
    BBL(bb0, s0, 0);
    BBL(bb1, s0, 1);
    CLUSTER(bb0, aB, 0);
    CLUSTER(bb1, aB, 1);
    asm volatile("s_waitcnt vmcnt(12)" ::: "memory");
    __builtin_amdgcn_s_barrier();
    { unsigned short* c = s0; s0 = s1; s1 = s2; s2 = c; }
  }

  // ---- tile 34 (A = aA) ----
  AG(35, aB);
  BBL(bb0, s0, 0);
  BBL(bb1, s0, 1);
  CLUSTER(bb0, aA, 0);
  CLUSTER(bb1, aA, 1);
  asm volatile("s_waitcnt vmcnt(8)" ::: "memory");      // forces stage(35) done
  __builtin_amdgcn_s_barrier();
  { unsigned short* c = s0; s0 = s1; s1 = s2; s2 = c; }
  // ---- tile 35 (A = aB) ----
  BBL(bb0, s0, 0);
  BBL(bb1, s0, 1);
  CLUSTER(bb0, aB, 0);
  CLUSTER(bb1, aB, 1);

  // epilogue: D col(px)=l&15, row(co)=(l>>4)*4+r
#pragma unroll
  for (int qm = 0; qm < 2; ++qm)
#pragma unroll
    for (int mi = 0; mi < 2; ++mi) {
      int cobase = qm * 128 + wv * 32 + mi * 16 + hi4 * 4;
      const float4 bv = *(const float4*)(bias + cobase);
#pragma unroll
      for (int ni = 0; ni < 8; ++ni) {
        int p = p0 + ni * 16 + lc;
        float* op = out + ((size_t)n * CO + cobase) * HWp + p;
        f32x4 v = acc[qm][mi][ni];
        op[0]               = v[0] + bv.x;
        op[(size_t)HWp]     = v[1] + bv.y;
        op[(size_t)2 * HWp] = v[2] + bv.z;
        op[(size_t)3 * HWp] = v[3] + bv.w;
      }
    }
}

extern "C" void kernel_launch(void* const* d_in, const int* in_sizes, int n_in,
                              void* d_out, int out_size, void* d_ws, size_t ws_size,
                              hipStream_t stream) {
  const int* mask = (const int*)d_in[0];
  const float* ori = (const float*)d_in[1];
  const float* weight = (const float*)d_in[2];
  const float* bias = (const float*)d_in[3];
  float* out = (float*)d_out;

  unsigned short* xp = (unsigned short*)d_ws;          // padded NHWC bf16, 107.5 MB
  unsigned short* w3 = xp + XPAD_ELEMS;                // 1.2 MB granule-ordered weights

  zero_border<<<644, 256, 0, stream>>>(xp);
  prep_w_kernel<<<(W3_ELEMS + 255) / 256, 256, 0, stream>>>(weight, w3);
  prep_x_kernel<<<B_ * Hh * 4 * 3, 256, 0, stream>>>(ori, mask, xp);
  sconv_gemm<<<1600, 256, 0, stream>>>(xp, w3, bias, out);
}

// Round 9
// 337.117 us; speedup vs baseline: 8.3096x; 1.5197x over previous
//
#include <hip/hip_runtime.h>

typedef __attribute__((ext_vector_type(8))) short short8;
typedef __attribute__((ext_vector_type(4))) float f32x4;

#define B_    8
#define CI    256
#define CO    256
#define Hh    160
#define Ww    160
#define HP    162
#define WP    162
#define HWp   (Hh * Ww)                 // 25600
#define XPAD_ELEMS (B_ * HP * WP * CI)  // 53,747,712 bf16
#define W3_ELEMS   (9 * CI * CO)        // 589,824 bf16 (granule order)
#define NT    36                        // 4 ci-chunks x 9 shifts, BK=64
#define BSLOT 8192                      // shorts per B slot: 128px x 64ci = 16KB

__device__ __forceinline__ unsigned short f2bf(float f) {
  unsigned int u = __float_as_uint(f);
  u += 0x7FFFu + ((u >> 16) & 1u);   // RNE
  return (unsigned short)(u >> 16);
}

// weight [co][ci][3][3] f32 -> w3 granules (same as r6/r7/r8):
// g = shift*128 + cic*32 + qm*16 + kk*8 + wm*2 + mi ; elem = g*512 + l*8 + e
// co = qm*128 + wm*32 + mi*16 + (l&15) ; ci = cic*64 + kk*32 + (l>>4)*8 + e
__global__ void prep_w_kernel(const float* __restrict__ w, unsigned short* __restrict__ w3) {
  int i = blockIdx.x * 256 + threadIdx.x;
  if (i >= W3_ELEMS) return;
  int e = i & 7, l = (i >> 3) & 63, g = i >> 9;
  int mi = g & 1, wm = (g >> 1) & 3, kk = (g >> 3) & 1;
  int qm = (g >> 4) & 1, cic = (g >> 5) & 3, shift = g >> 7;
  int co = qm * 128 + wm * 32 + mi * 16 + (l & 15);
  int ci = cic * 64 + kk * 32 + (l >> 4) * 8 + e;
  w3[i] = f2bf(w[(co * 256 + ci) * 9 + shift]);
}

// zero the padded border of xp
__global__ void zero_border(unsigned short* __restrict__ xp) {
  int g = blockIdx.x * 256 + threadIdx.x;
  int pos = g >> 5;
  int c = (g & 31) << 3;
  int n = pos / 644;
  int p = pos - n * 644;
  int y, x;
  if (p < 324) { y = (p < 162) ? 0 : 161; x = (p < 162) ? p : p - 162; }
  else { int q = p - 324; y = 1 + (q >> 1); x = (q & 1) ? 161 : 0; }
  unsigned short* d = xp + (((size_t)(n * 162 + y)) * 162 + x) * 256 + c;
  *(uint4*)d = (uint4){0u, 0u, 0u, 0u};
}

// ori [n][ci][h][w] f32 * mask -> xp [n][h+1][w+1][ci] bf16 (padded NHWC)
__global__ void prep_x_kernel(const float* __restrict__ ori, const int* __restrict__ mask,
                              unsigned short* __restrict__ xp) {
  int bid = blockIdx.x;                 // ((n*160+h)*4+cit)*3+wt
  int wt = bid % 3;
  int t1 = bid / 3;
  int cit = t1 & 3;
  int t2 = t1 >> 2;
  int h = t2 % Hh;
  int n = t2 / Hh;
  int t = threadIdx.x;

  __shared__ float tile[64][65];

  int wl = t & 63;
  int w = wt * 64 + wl;
  bool valid = (w < Ww);
  float m = 0.f;
  if (valid) m = (float)mask[(n * Hh + h) * Ww + w];
  const float* src = ori + (((size_t)(n * CI + cit * 64) * Hh + h) * Ww + w);
  int r0 = t >> 6;
#pragma unroll
  for (int k = 0; k < 16; ++k) {
    int ci_l = r0 * 16 + k;
    float v = 0.f;
    if (valid) v = src[(size_t)ci_l * HWp] * m;
    tile[ci_l][wl] = v;
  }
  __syncthreads();

  int wl2 = t >> 2;
  int wo = wt * 64 + wl2;
  if (wo < Ww) {
    int cseg = (t & 3) * 16;
    union { unsigned short u[8]; uint4 v; } p0, p1;
#pragma unroll
    for (int j = 0; j < 8; ++j) p0.u[j] = f2bf(tile[cseg + j][wl2]);
#pragma unroll
    for (int j = 0; j < 8; ++j) p1.u[j] = f2bf(tile[cseg + 8 + j][wl2]);
    unsigned short* dst = xp + ((size_t)((n * HP + h + 1) * WP) + (wo + 1)) * CI + cit * 64 + cseg;
    *(uint4*)dst = p0.v;
    *(uint4*)(dst + 8) = p1.v;
  }
}

__device__ __forceinline__ void gload16(const unsigned short* g, unsigned short* l) {
  __builtin_amdgcn_global_load_lds((const __attribute__((address_space(1))) void*)g,
                                   (__attribute__((address_space(3))) void*)l, 16, 0, 0);
}

// Implicit GEMM: A(weights) single-buffered to regs from w3 (L2-hot), B in 3-slot LDS ring.
// Block 256co x 128px, 256 thr = 4 waves; per-wave qm(2)xmi(2) co-frags x 8 px-frags.
// acc[2][2][8] f32x4 (128) + aA (32) + bbA/bbB ping-pong (32) ~= 215 regs -> NO spill
// (r8 had +64 for A/bb double-buffers -> 285 > 256 -> 600MB scratch writes).
// Per tile: AG(tt) -> STAGE(tt+2) -> {BBL4,BBL4,CL16,BBL4,CL16,BBL4,CL16,CL16}
// -> vmcnt(4) -> raw s_barrier.  aA's compiler wait (vmcnt(4)) drains stage(tt+1);
// stage(tt+2)'s 4 loads fly across the barrier (T4, never drains to 0 mid-loop).
__global__ void __launch_bounds__(256, 2)
sconv_gemm(const unsigned short* __restrict__ xp, const unsigned short* __restrict__ w3,
           const float* __restrict__ bias, float* __restrict__ out) {
  __shared__ unsigned short Bs[3][BSLOT];   // 48KB

  const int bid = blockIdx.x;
  const int n = bid & 7;          // image per XCD (1600 = 8 x 200)
  const int pxt = bid >> 3;       // 0..199
  const int p0 = pxt * 128;       // first pixel (within image)

  const int t = threadIdx.x;
  const int l = t & 63;
  const int wv = t >> 6;

  const int lr = l >> 3;
  const int swz8 = ((l & 7) ^ lr) << 3;   // proven source pre-swizzle (shorts)
  const int lc = l & 15, hi4 = l >> 4, lx7 = l & 7;

  // B staging: wave wv covers px rows [wv*32, wv*32+32), granule g = 8 rows
  unsigned boff[4];
#pragma unroll
  for (int g = 0; g < 4; ++g) {
    int p = p0 + wv * 32 + g * 8 + lr;
    int h = p / Ww;
    int w = p - h * Ww;
    boff[g] = (unsigned)((n * HP + h) * WP + w) * 256 + swz8;
  }

  f32x4 acc[2][2][8];
#pragma unroll
  for (int a = 0; a < 2; ++a)
#pragma unroll
    for (int b = 0; b < 2; ++b)
#pragma unroll
      for (int c = 0; c < 8; ++c)
        acc[a][b][c] = (f32x4){0.f, 0.f, 0.f, 0.f};

  auto STAGE = [&](int ts, unsigned short* slot) {
    int cic = (ts * 57) >> 9;            // ts/9
    int sh = ts - cic * 9;
    int kh = (sh * 11) >> 5;             // sh/3
    int kw = sh - kh * 3;
    const unsigned short* src = xp + (unsigned)(kh * WP + kw) * 256 + (cic << 6);
    unsigned short* dst = slot + wv * 2048;
#pragma unroll
    for (int g = 0; g < 4; ++g)
      gload16(src + boff[g], dst + g * 512);
  };

  // A granules -> a[qm*4 + kk*2 + mi]
  auto AG = [&](int ts, short8* a) {
    int cic = (ts * 57) >> 9;
    int sh = ts - cic * 9;
    const unsigned short* p = w3 + (((unsigned)(sh * 128 + cic * 32 + wv * 2)) << 9) + (l << 3);
    a[0] = *(const short8*)(p);
    a[1] = *(const short8*)(p + 512);
    a[2] = *(const short8*)(p + 4096);
    a[3] = *(const short8*)(p + 4096 + 512);
    a[4] = *(const short8*)(p + 8192);
    a[5] = *(const short8*)(p + 8192 + 512);
    a[6] = *(const short8*)(p + 8192 + 4096);
    a[7] = *(const short8*)(p + 8192 + 4096 + 512);
  };

#define BBL4(dst, slot, kk, nb) do {                                          \
  _Pragma("unroll")                                                           \
  for (int ni = 0; ni < 4; ++ni)                                              \
    dst[ni] = *(const short8*)((slot) + (((nb) + ni) * 16 + lc) * 64 +        \
                               (((((kk) << 2) + hi4) ^ lx7) << 3));           \
} while (0)

#define CL16(A, kk, bb, nb) do {                                              \
  __builtin_amdgcn_s_setprio(1);                                              \
  _Pragma("unroll")                                                           \
  for (int qm = 0; qm < 2; ++qm)                                              \
    _Pragma("unroll")                                                         \
    for (int mi = 0; mi < 2; ++mi)                                            \
      _Pragma("unroll")                                                       \
      for (int ni = 0; ni < 4; ++ni)                                          \
        acc[qm][mi][(nb) + ni] = __builtin_amdgcn_mfma_f32_16x16x32_bf16(     \
            A[qm * 4 + (kk) * 2 + mi], bb[ni], acc[qm][mi][(nb) + ni], 0, 0, 0); \
  __builtin_amdgcn_s_setprio(0);                                              \
} while (0)

  short8 aA[8], bbA[4], bbB[4];

  // TILE(tt): cur = slot tt%3, stage dest = slot (tt+2)%3
#define TILE(tt, cur, sdst, WN) do {                                          \
  AG((tt), aA);                        /* 8 global->reg, L2-hot */            \
  if ((tt) + 2 < NT) STAGE((tt) + 2, (sdst));                                 \
  BBL4(bbA, (cur), 0, 0);                                                     \
  BBL4(bbB, (cur), 0, 4);                                                     \
  CL16(aA, 0, bbA, 0);                                                        \
  BBL4(bbA, (cur), 1, 0);                                                     \
  CL16(aA, 0, bbB, 4);                                                        \
  BBL4(bbB, (cur), 1, 4);                                                     \
  CL16(aA, 1, bbA, 0);                                                        \
  CL16(aA, 1, bbB, 4);                                                        \
  asm volatile("s_waitcnt vmcnt(" #WN ")" ::: "memory");                      \
  __builtin_amdgcn_s_barrier();                                               \
} while (0)

  unsigned short* const s0 = &Bs[0][0];
  unsigned short* const s1 = &Bs[1][0];
  unsigned short* const s2 = &Bs[2][0];

  // prologue: stage slots 0,1; wait slot0 only (slot1's 4 stay in flight)
  STAGE(0, s0);
  STAGE(1, s1);
  asm volatile("s_waitcnt vmcnt(4)" ::: "memory");
  __builtin_amdgcn_s_barrier();

  // 36 tiles = 11 x 3 + 3 peeled (tiles 33,34,35)
  for (int t3 = 0; t3 < 33; t3 += 3) {
    TILE(t3 + 0, s0, s2, 4);
    TILE(t3 + 1, s1, s0, 4);
    TILE(t3 + 2, s2, s1, 4);
  }
  TILE(33, s0, s2, 4);
  TILE(34, s1, s0, 0);     // no STAGE(36); drain stage(35) fully
  // tile 35: no stage, no barrier needed after
  {
    AG(35, aA);
    BBL4(bbA, s2, 0, 0);
    BBL4(bbB, s2, 0, 4);
    CL16(aA, 0, bbA, 0);
    BBL4(bbA, s2, 1, 0);
    CL16(aA, 0, bbB, 4);
    BBL4(bbB, s2, 1, 4);
    CL16(aA, 1, bbA, 0);
    CL16(aA, 1, bbB, 4);
  }

  // epilogue: D col(px)=l&15, row(co)=(l>>4)*4+r
#pragma unroll
  for (int qm = 0; qm < 2; ++qm)
#pragma unroll
    for (int mi = 0; mi < 2; ++mi) {
      int cobase = qm * 128 + wv * 32 + mi * 16 + hi4 * 4;
      const float4 bv = *(const float4*)(bias + cobase);
#pragma unroll
      for (int ni = 0; ni < 8; ++ni) {
        int p = p0 + ni * 16 + lc;
        float* op = out + ((size_t)n * CO + cobase) * HWp + p;
        f32x4 v = acc[qm][mi][ni];
        op[0]               = v[0] + bv.x;
        op[(size_t)HWp]     = v[1] + bv.y;
        op[(size_t)2 * HWp] = v[2] + bv.z;
        op[(size_t)3 * HWp] = v[3] + bv.w;
      }
    }
}

extern "C" void kernel_launch(void* const* d_in, const int* in_sizes, int n_in,
                              void* d_out, int out_size, void* d_ws, size_t ws_size,
                              hipStream_t stream) {
  const int* mask = (const int*)d_in[0];
  const float* ori = (const float*)d_in[1];
  const float* weight = (const float*)d_in[2];
  const float* bias = (const float*)d_in[3];
  float* out = (float*)d_out;

  unsigned short* xp = (unsigned short*)d_ws;          // padded NHWC bf16, 107.5 MB
  unsigned short* w3 = xp + XPAD_ELEMS;                // 1.2 MB granule-ordered weights

  zero_border<<<644, 256, 0, stream>>>(xp);
  prep_w_kernel<<<(W3_ELEMS + 255) / 256, 256, 0, stream>>>(weight, w3);
  prep_x_kernel<<<B_ * Hh * 4 * 3, 256, 0, stream>>>(ori, mask, xp);
  sconv_gemm<<<1600, 256, 0, stream>>>(xp, w3, bias, out);
}

// Round 11
// 319.525 us; speedup vs baseline: 8.7671x; 1.0551x over previous
//
#include <hip/hip_runtime.h>

typedef __attribute__((ext_vector_type(8))) short short8;
typedef __attribute__((ext_vector_type(4))) float f32x4;

#define B_    8
#define CI    256
#define CO    256
#define Hh    160
#define Ww    160
#define HP    162
#define WP    162
#define HWp   (Hh * Ww)                 // 25600
#define XPAD_ELEMS (B_ * HP * WP * CI)  // 53,747,712 bf16
#define W3_ELEMS   (9 * CI * CO)        // 589,824 bf16 (granule order)
#define NT    36                        // 4 ci-chunks x 9 shifts, BK=64
#define BSLOT (160 * 64)                // shorts per B slot: 160px x 64ci = 20KB

__device__ __forceinline__ unsigned short f2bf(float f) {
  unsigned int u = __float_as_uint(f);
  u += 0x7FFFu + ((u >> 16) & 1u);   // RNE
  return (unsigned short)(u >> 16);
}

// weight [co][ci][3][3] f32 -> w3 granules (same layout as r6-r10):
// g = shift*128 + cic*32 + qm*16 + kk*8 + wm*2 + mi ; elem = g*512 + l*8 + e
// co = qm*128 + wm*32 + mi*16 + (l&15) ; ci = cic*64 + kk*32 + (l>>4)*8 + e
__global__ void prep_w_kernel(const float* __restrict__ w, unsigned short* __restrict__ w3) {
  int i = blockIdx.x * 256 + threadIdx.x;
  if (i >= W3_ELEMS) return;
  int e = i & 7, l = (i >> 3) & 63, g = i >> 9;
  int mi = g & 1, wm = (g >> 1) & 3, kk = (g >> 3) & 1;
  int qm = (g >> 4) & 1, cic = (g >> 5) & 3, shift = g >> 7;
  int co = qm * 128 + wm * 32 + mi * 16 + (l & 15);
  int ci = cic * 64 + kk * 32 + (l >> 4) * 8 + e;
  w3[i] = f2bf(w[(co * 256 + ci) * 9 + shift]);
}

// zero the padded border of xp
__global__ void zero_border(unsigned short* __restrict__ xp) {
  int g = blockIdx.x * 256 + threadIdx.x;
  int pos = g >> 5;
  int c = (g & 31) << 3;
  int n = pos / 644;
  int p = pos - n * 644;
  int y, x;
  if (p < 324) { y = (p < 162) ? 0 : 161; x = (p < 162) ? p : p - 162; }
  else { int q = p - 324; y = 1 + (q >> 1); x = (q & 1) ? 161 : 0; }
  unsigned short* d = xp + (((size_t)(n * 162 + y)) * 162 + x) * 256 + c;
  *(uint4*)d = (uint4){0u, 0u, 0u, 0u};
}

// ori [n][ci][h][w] f32 * mask -> xp [n][h+1][w+1][ci] bf16 (padded NHWC)
__global__ void prep_x_kernel(const float* __restrict__ ori, const int* __restrict__ mask,
                              unsigned short* __restrict__ xp) {
  int bid = blockIdx.x;                 // ((n*160+h)*4+cit)*3+wt
  int wt = bid % 3;
  int t1 = bid / 3;
  int cit = t1 & 3;
  int t2 = t1 >> 2;
  int h = t2 % Hh;
  int n = t2 / Hh;
  int t = threadIdx.x;

  __shared__ float tile[64][65];

  int wl = t & 63;
  int w = wt * 64 + wl;
  bool valid = (w < Ww);
  float m = 0.f;
  if (valid) m = (float)mask[(n * Hh + h) * Ww + w];
  const float* src = ori + (((size_t)(n * CI + cit * 64) * Hh + h) * Ww + w);
  int r0 = t >> 6;
#pragma unroll
  for (int k = 0; k < 16; ++k) {
    int ci_l = r0 * 16 + k;
    float v = 0.f;
    if (valid) v = src[(size_t)ci_l * HWp] * m;
    tile[ci_l][wl] = v;
  }
  __syncthreads();

  int wl2 = t >> 2;
  int wo = wt * 64 + wl2;
  if (wo < Ww) {
    int cseg = (t & 3) * 16;
    union { unsigned short u[8]; uint4 v; } p0, p1;
#pragma unroll
    for (int j = 0; j < 8; ++j) p0.u[j] = f2bf(tile[cseg + j][wl2]);
#pragma unroll
    for (int j = 0; j < 8; ++j) p1.u[j] = f2bf(tile[cseg + 8 + j][wl2]);
    unsigned short* dst = xp + ((size_t)((n * HP + h + 1) * WP) + (wo + 1)) * CI + cit * 64 + cseg;
    *(uint4*)dst = p0.v;
    *(uint4*)(dst + 8) = p1.v;
  }
}

__device__ __forceinline__ void gload16(const unsigned short* g, unsigned short* l) {
  __builtin_amdgcn_global_load_lds((const __attribute__((address_space(1))) void*)g,
                                   (__attribute__((address_space(3))) void*)l, 16, 0, 0);
}

// Implicit GEMM, m201-style phase skeleton on r9's data plan.
// Block 256 thr / 4 waves; 256co x 160px (one image row). Wave: 64co x 160px,
// acc[4][10] f32x4. A direct-to-reg from w3 (L2-hot), SPLIT by kk half:
//   aK0 (kk=0) last used phase 1 -> AGK0(t+1) issued in phase 2 ISSUES;
//   aK1 (kk=1) last used phase 3 -> AGK1(t+1) issued in phase 3 ENDW after CL.
// (r10 bug: AG(t+1) in phase-3 ISSUES overwrote aA before phase-3's CL -> wrong weights.)
// B: 3-slot 20KB LDS ring, 5 gload_lds/tile spread over phases. Per tile, 4 phases:
// {issue VMEM -> 5 ds_read -> s_barrier -> lgkmcnt(0) -> setprio(1) -> 20 MFMA ->
//  setprio(0) -> s_barrier}; ONE counted vmcnt(13)/tile. LDS 60KB, 2 blocks/CU.
// Grid 1280 = 8 img (XCD-owned) x 160 rows.
__global__ void __launch_bounds__(256, 2)
sconv_gemm(const unsigned short* __restrict__ xp, const unsigned short* __restrict__ w3,
           const float* __restrict__ bias, float* __restrict__ out) {
  __shared__ unsigned short Bs[3][BSLOT];   // 60KB

  const int bid = blockIdx.x;
  const int n = bid & 7;          // image per XCD
  const int h = bid >> 3;         // output row

  const int t = threadIdx.x;
  const int l = t & 63;
  const int wv = t >> 6;

  const int lr = l >> 3;
  const int swz8 = ((l & 7) ^ lr) << 3;   // proven source pre-swizzle (shorts)
  const int lc = l & 15, hi4 = l >> 4, lx7 = l & 7;
  const unsigned xrow = (unsigned)(n * HP + h);

  // stage lane offsets: call k covers px rows [k*32, k*32+32); wave wv rows +wv*8
  unsigned boff[5];
#pragma unroll
  for (int k = 0; k < 5; ++k)
    boff[k] = (unsigned)(k * 32 + wv * 8 + lr) * 256 + swz8;

  f32x4 acc[4][10];
#pragma unroll
  for (int j = 0; j < 4; ++j)
#pragma unroll
    for (int ni = 0; ni < 10; ++ni)
      acc[j][ni] = (f32x4){0.f, 0.f, 0.f, 0.f};

  short8 aK0[4], aK1[4], bb[5];

  // K-tile ts -> (cic outer, shift inner) geometry
#define TPAR(ts, cic, sh, kh, kw)                                             \
  const int cic = ((ts) * 57) >> 9;                                           \
  const int sh = (ts) - cic * 9;                                              \
  const int kh = (sh * 11) >> 5;                                              \
  const int kw = sh - kh * 3;

  auto STG = [&](int ts, unsigned short* slot, int k) {
    TPAR(ts, cic, sh, kh, kw)
    (void)sh;
    const unsigned short* src = xp + ((size_t)(xrow + kh) * WP + kw) * 256 + (cic << 6) + boff[k];
    gload16(src, slot + (k * 32 + wv * 8) * 64);
  };

  // load one kk-half of A fragments (4 x short8)
  auto AGH = [&](int ts, int kk, short8* dst) {
    TPAR(ts, cic, sh, kh, kw)
    (void)kh; (void)kw;
    const unsigned short* p = w3 +
        ((size_t)(sh * 128 + cic * 32 + (wv >> 1) * 16 + ((wv & 1) << 2) + kk * 8) << 9) + (l << 3);
#pragma unroll
    for (int j = 0; j < 4; ++j)
      dst[j] = *(const short8*)(p + (j << 9));
  };

#define BBR(slot, kk, nb) do {                                                \
  _Pragma("unroll")                                                           \
  for (int i = 0; i < 5; ++i)                                                 \
    bb[i] = *(const short8*)((slot) + (((nb) + i) * 16 + lc) * 64 +           \
                             (((((kk) << 2) + hi4) ^ lx7) << 3));             \
} while (0)

#define CL(AH, nb) do {                                                       \
  __builtin_amdgcn_s_setprio(1);                                              \
  _Pragma("unroll")                                                           \
  for (int j = 0; j < 4; ++j)                                                 \
    _Pragma("unroll")                                                         \
    for (int i = 0; i < 5; ++i)                                               \
      acc[j][(nb) + i] = __builtin_amdgcn_mfma_f32_16x16x32_bf16(             \
          AH[j], bb[i], acc[j][(nb) + i], 0, 0, 0);                           \
  __builtin_amdgcn_s_setprio(0);                                              \
} while (0)

  // phase skeleton (m201): issues -> ds_reads -> barrier -> lgkm(0) -> MFMA -> barrier
#define PH(slot, kk, AH, nb, ISSUES, ENDW) do {                               \
  ISSUES                                                                      \
  BBR(slot, kk, nb);                                                          \
  __builtin_amdgcn_s_barrier();                                               \
  asm volatile("s_waitcnt lgkmcnt(0)" ::: "memory");                          \
  __builtin_amdgcn_sched_barrier(0);                                          \
  CL(AH, nb);                                                                 \
  ENDW                                                                        \
  __builtin_amdgcn_s_barrier();                                               \
} while (0)

  // full tile: stages (t+2) into sn; A(t+1) halves at their hazard-free points
#define TILE(tt, sc, sn) do {                                                 \
  PH(sc, 0, aK0, 0, { STG((tt) + 2, sn, 0); STG((tt) + 2, sn, 1); }, {});     \
  PH(sc, 0, aK0, 5, { STG((tt) + 2, sn, 2); }, {});                           \
  PH(sc, 1, aK1, 0, { AGH((tt) + 1, 0, aK0); STG((tt) + 2, sn, 3); }, {});    \
  PH(sc, 1, aK1, 5, { STG((tt) + 2, sn, 4); },                                \
     { AGH((tt) + 1, 1, aK1);                                                 \
       asm volatile("s_waitcnt vmcnt(13)" ::: "memory"); });                  \
} while (0)

  unsigned short* const s0 = &Bs[0][0];
  unsigned short* const s1 = &Bs[1][0];
  unsigned short* const s2 = &Bs[2][0];

  // prologue: stage tiles 0,1; load A(0); keep st(1)5 + A(0)8 = 13 in flight
  for (int k = 0; k < 5; ++k) STG(0, s0, k);
  for (int k = 0; k < 5; ++k) STG(1, s1, k);
  AGH(0, 0, aK0);
  AGH(0, 1, aK1);
  asm volatile("s_waitcnt vmcnt(13)" ::: "memory");
  __builtin_amdgcn_s_barrier();

  // tiles 0..33 staged; 34,35 peeled (no staging)
  for (int t3 = 0; t3 < 33; t3 += 3) {
    TILE(t3 + 0, s0, s2);
    TILE(t3 + 1, s1, s0);
    TILE(t3 + 2, s2, s1);
  }
  TILE(33, s0, s2);
  // tile 34 (slot s1): A(35) halves at the same hazard-free points
  PH(s1, 0, aK0, 0, {}, {});
  PH(s1, 0, aK0, 5, {}, {});
  PH(s1, 1, aK1, 0, { AGH(35, 0, aK0); }, {});
  PH(s1, 1, aK1, 5, {},
     { AGH(35, 1, aK1);
       asm volatile("s_waitcnt vmcnt(8)" ::: "memory"); });   // STG(35) drained
  // tile 35 (slot s2): final, no trailing sync
  PH(s2, 0, aK0, 0, {}, {});
  PH(s2, 0, aK0, 5, {}, {});
  PH(s2, 1, aK1, 0, {}, {});
  {
    BBR(s2, 1, 5);
    asm volatile("s_waitcnt lgkmcnt(0)" ::: "memory");
    __builtin_amdgcn_sched_barrier(0);
    CL(aK1, 5);
  }

  // epilogue: D col(px)=l&15, row(co)=(l>>4)*4+r; wave covers co [wv*64, wv*64+64)
#pragma unroll
  for (int j = 0; j < 4; ++j) {
    int cobase = wv * 64 + j * 16 + hi4 * 4;
    const float4 bv = *(const float4*)(bias + cobase);
    float* op = out + (((size_t)n * CO + cobase) * Hh + h) * Ww;
#pragma unroll
    for (int ni = 0; ni < 10; ++ni) {
      int w = ni * 16 + lc;
      f32x4 v = acc[j][ni];
      op[w]                   = v[0] + bv.x;
      op[(size_t)HWp + w]     = v[1] + bv.y;
      op[(size_t)2 * HWp + w] = v[2] + bv.z;
      op[(size_t)3 * HWp + w] = v[3] + bv.w;
    }
  }
}

extern "C" void kernel_launch(void* const* d_in, const int* in_sizes, int n_in,
                              void* d_out, int out_size, void* d_ws, size_t ws_size,
                              hipStream_t stream) {
  const int* mask = (const int*)d_in[0];
  const float* ori = (const float*)d_in[1];
  const float* weight = (const float*)d_in[2];
  const float* bias = (const float*)d_in[3];
  float* out = (float*)d_out;

  unsigned short* xp = (unsigned short*)d_ws;          // padded NHWC bf16, 107.5 MB
  unsigned short* w3 = xp + XPAD_ELEMS;                // 1.2 MB granule-ordered weights

  zero_border<<<644, 256, 0, stream>>>(xp);
  prep_w_kernel<<<(W3_ELEMS + 255) / 256, 256, 0, stream>>>(weight, w3);
  prep_x_kernel<<<B_ * Hh * 4 * 3, 256, 0, stream>>>(ori, mask, xp);
  sconv_gemm<<<1280, 256, 0, stream>>>(xp, w3, bias, out);
}

// Round 12
// 309.057 us; speedup vs baseline: 9.0640x; 1.0339x over previous
//
#include <hip/hip_runtime.h>

typedef __attribute__((ext_vector_type(8))) short short8;
typedef __attribute__((ext_vector_type(4))) float f32x4;

#define B_    8
#define CI    256
#define CO    256
#define Hh    160
#define Ww    160
#define HP    162
#define WP    162
#define HWp   (Hh * Ww)                 // 25600
#define XPAD_ELEMS (B_ * HP * WP * CI)  // 53,747,712 bf16
#define W3_ELEMS   (9 * CI * CO)        // 589,824 bf16 (granule order)
#define NT    36                        // 4 ci-chunks x 9 shifts, BK=64
#define BSLOT (160 * 64)                // shorts per B slot: 160px x 64ci = 20KB

// fused prep grid partition
#define NBORD 644
#define NPW   2304                      // 589824 / 256
#define NPX   (B_ * Hh * 4 * 3)        // 15360

__device__ __forceinline__ unsigned short f2bf(float f) {
  unsigned int u = __float_as_uint(f);
  u += 0x7FFFu + ((u >> 16) & 1u);   // RNE
  return (unsigned short)(u >> 16);
}

// One launch: zero xp border | weight->w3 granules | ori*mask->xp packed NHWC bf16
// w3 granule layout (same as r6-r11):
// g = shift*128 + cic*32 + qm*16 + kk*8 + wm*2 + mi ; elem = g*512 + l*8 + e
// co = qm*128 + wm*32 + mi*16 + (l&15) ; ci = cic*64 + kk*32 + (l>>4)*8 + e
__global__ void prep_all(const float* __restrict__ ori, const int* __restrict__ mask,
                         const float* __restrict__ w,
                         unsigned short* __restrict__ xp, unsigned short* __restrict__ w3) {
  __shared__ float tile[64][65];
  const int bid = blockIdx.x;
  const int t = threadIdx.x;

  if (bid < NBORD) {
    // zero the padded border of xp (rows 0,161 and cols 0,161 per image)
    int g = bid * 256 + t;
    int pos = g >> 5;
    int c = (g & 31) << 3;
    int n = pos / 644;
    int p = pos - n * 644;
    int y, x;
    if (p < 324) { y = (p < 162) ? 0 : 161; x = (p < 162) ? p : p - 162; }
    else { int q = p - 324; y = 1 + (q >> 1); x = (q & 1) ? 161 : 0; }
    unsigned short* d = xp + (((size_t)(n * 162 + y)) * 162 + x) * 256 + c;
    *(uint4*)d = (uint4){0u, 0u, 0u, 0u};
    return;
  }
  if (bid < NBORD + NPW) {
    int i = (bid - NBORD) * 256 + t;
    int e = i & 7, l = (i >> 3) & 63, g = i >> 9;
    int mi = g & 1, wm = (g >> 1) & 3, kk = (g >> 3) & 1;
    int qm = (g >> 4) & 1, cic = (g >> 5) & 3, shift = g >> 7;
    int co = qm * 128 + wm * 32 + mi * 16 + (l & 15);
    int ci = cic * 64 + kk * 32 + (l >> 4) * 8 + e;
    w3[i] = f2bf(w[(co * 256 + ci) * 9 + shift]);
    return;
  }

  // prep_x: bid2 = ((n*160+h)*4+cit)*3+wt
  int bid2 = bid - (NBORD + NPW);
  int wt = bid2 % 3;
  int t1 = bid2 / 3;
  int cit = t1 & 3;
  int t2 = t1 >> 2;
  int h = t2 % Hh;
  int n = t2 / Hh;

  int wl = t & 63;
  int ww = wt * 64 + wl;
  bool valid = (ww < Ww);
  float m = 0.f;
  if (valid) m = (float)mask[(n * Hh + h) * Ww + ww];
  const float* src = ori + (((size_t)(n * CI + cit * 64) * Hh + h) * Ww + ww);
  int r0 = t >> 6;
#pragma unroll
  for (int k = 0; k < 16; ++k) {
    int ci_l = r0 * 16 + k;
    float v = 0.f;
    if (valid) v = src[(size_t)ci_l * HWp] * m;
    tile[ci_l][wl] = v;
  }
  __syncthreads();

  int wl2 = t >> 2;
  int wo = wt * 64 + wl2;
  if (wo < Ww) {
    int cseg = (t & 3) * 16;
    union { unsigned short u[8]; uint4 v; } p0, p1;
#pragma unroll
    for (int j = 0; j < 8; ++j) p0.u[j] = f2bf(tile[cseg + j][wl2]);
#pragma unroll
    for (int j = 0; j < 8; ++j) p1.u[j] = f2bf(tile[cseg + 8 + j][wl2]);
    unsigned short* dst = xp + ((size_t)((n * HP + h + 1) * WP) + (wo + 1)) * CI + cit * 64 + cseg;
    *(uint4*)dst = p0.v;
    *(uint4*)(dst + 8) = p1.v;
  }
}

__device__ __forceinline__ void gload16(const unsigned short* g, unsigned short* l) {
  __builtin_amdgcn_global_load_lds((const __attribute__((address_space(1))) void*)g,
                                   (__attribute__((address_space(3))) void*)l, 16, 0, 0);
}

// Implicit GEMM, phase skeleton (r11) with the intra-phase pin REMOVED:
// per phase {issue VMEM -> 5 ds_read -> s_barrier -> setprio(1) -> 20 MFMA ->
// setprio(0) -> s_barrier}; compiler now emits fine-grained lgkmcnt(4/3/1/0),
// overlapping the read tail with the first MFMAs (m97 behavior; r11's explicit
// lgkmcnt(0)+sched_barrier serialized each phase). ONE counted vmcnt(13)/tile.
// A direct-to-reg split by kk half (aK0 refilled ph2, aK1 in ph3 ENDW after CL).
// B: 3-slot 20KB LDS ring. Block 256thr/4 waves = 256co x 160px (one image row),
// wave 64co x 160px, acc[4][10] f32x4. LDS 60KB, 2 blocks/CU. Grid 1280.
__global__ void __launch_bounds__(256, 2)
sconv_gemm(const unsigned short* __restrict__ xp, const unsigned short* __restrict__ w3,
           const float* __restrict__ bias, float* __restrict__ out) {
  __shared__ unsigned short Bs[3][BSLOT];   // 60KB

  const int bid = blockIdx.x;
  const int n = bid & 7;          // image per XCD
  const int h = bid >> 3;         // output row

  const int t = threadIdx.x;
  const int l = t & 63;
  const int wv = t >> 6;

  const int lr = l >> 3;
  const int swz8 = ((l & 7) ^ lr) << 3;   // proven source pre-swizzle (shorts)
  const int lc = l & 15, hi4 = l >> 4, lx7 = l & 7;
  const unsigned xrow = (unsigned)(n * HP + h);

  // stage lane offsets: call k covers px rows [k*32, k*32+32); wave wv rows +wv*8
  unsigned boff[5];
#pragma unroll
  for (int k = 0; k < 5; ++k)
    boff[k] = (unsigned)(k * 32 + wv * 8 + lr) * 256 + swz8;

  f32x4 acc[4][10];
#pragma unroll
  for (int j = 0; j < 4; ++j)
#pragma unroll
    for (int ni = 0; ni < 10; ++ni)
      acc[j][ni] = (f32x4){0.f, 0.f, 0.f, 0.f};

  short8 aK0[4], aK1[4], bb[5];

#define TPAR(ts, cic, sh, kh, kw)                                             \
  const int cic = ((ts) * 57) >> 9;                                           \
  const int sh = (ts) - cic * 9;                                              \
  const int kh = (sh * 11) >> 5;                                              \
  const int kw = sh - kh * 3;

  auto STG = [&](int ts, unsigned short* slot, int k) {
    TPAR(ts, cic, sh, kh, kw)
    (void)sh;
    const unsigned short* src = xp + ((size_t)(xrow + kh) * WP + kw) * 256 + (cic << 6) + boff[k];
    gload16(src, slot + (k * 32 + wv * 8) * 64);
  };

  auto AGH = [&](int ts, int kk, short8* dst) {
    TPAR(ts, cic, sh, kh, kw)
    (void)kh; (void)kw;
    const unsigned short* p = w3 +
        ((size_t)(sh * 128 + cic * 32 + (wv >> 1) * 16 + ((wv & 1) << 2) + kk * 8) << 9) + (l << 3);
#pragma unroll
    for (int j = 0; j < 4; ++j)
      dst[j] = *(const short8*)(p + (j << 9));
  };

#define BBR(slot, kk, nb) do {                                                \
  _Pragma("unroll")                                                           \
  for (int i = 0; i < 5; ++i)                                                 \
    bb[i] = *(const short8*)((slot) + (((nb) + i) * 16 + lc) * 64 +           \
                             (((((kk) << 2) + hi4) ^ lx7) << 3));             \
} while (0)

#define CL(AH, nb) do {                                                       \
  __builtin_amdgcn_s_setprio(1);                                              \
  _Pragma("unroll")                                                           \
  for (int j = 0; j < 4; ++j)                                                 \
    _Pragma("unroll")                                                         \
    for (int i = 0; i < 5; ++i)                                               \
      acc[j][(nb) + i] = __builtin_amdgcn_mfma_f32_16x16x32_bf16(             \
          AH[j], bb[i], acc[j][(nb) + i], 0, 0, 0);                           \
  __builtin_amdgcn_s_setprio(0);                                              \
} while (0)

  // phase: issues -> ds_reads -> barrier -> MFMA (compiler-counted lgkm) -> barrier
#define PH(slot, kk, AH, nb, ISSUES, ENDW) do {                               \
  ISSUES                                                                      \
  BBR(slot, kk, nb);                                                          \
  __builtin_amdgcn_s_barrier();                                               \
  CL(AH, nb);                                                                 \
  ENDW                                                                        \
  __builtin_amdgcn_s_barrier();                                               \
} while (0)

#define TILE(tt, sc, sn) do {                                                 \
  PH(sc, 0, aK0, 0, { STG((tt) + 2, sn, 0); STG((tt) + 2, sn, 1); }, {});     \
  PH(sc, 0, aK0, 5, { STG((tt) + 2, sn, 2); }, {});                           \
  PH(sc, 1, aK1, 0, { AGH((tt) + 1, 0, aK0); STG((tt) + 2, sn, 3); }, {});    \
  PH(sc, 1, aK1, 5, { STG((tt) + 2, sn, 4); },                                \
     { AGH((tt) + 1, 1, aK1);                                                 \
       asm volatile("s_waitcnt vmcnt(13)" ::: "memory"); });                  \
} while (0)

  unsigned short* const s0 = &Bs[0][0];
  unsigned short* const s1 = &Bs[1][0];
  unsigned short* const s2 = &Bs[2][0];

  // prologue: stage tiles 0,1; load A(0); keep st(1)5 + A(0)8 = 13 in flight
  for (int k = 0; k < 5; ++k) STG(0, s0, k);
  for (int k = 0; k < 5; ++k) STG(1, s1, k);
  AGH(0, 0, aK0);
  AGH(0, 1, aK1);
  asm volatile("s_waitcnt vmcnt(13)" ::: "memory");
  __builtin_amdgcn_s_barrier();

  // tiles 0..33 staged; 34,35 peeled (no staging)
  for (int t3 = 0; t3 < 33; t3 += 3) {
    TILE(t3 + 0, s0, s2);
    TILE(t3 + 1, s1, s0);
    TILE(t3 + 2, s2, s1);
  }
  TILE(33, s0, s2);
  // tile 34 (slot s1): A(35) halves at the hazard-free points
  PH(s1, 0, aK0, 0, {}, {});
  PH(s1, 0, aK0, 5, {}, {});
  PH(s1, 1, aK1, 0, { AGH(35, 0, aK0); }, {});
  PH(s1, 1, aK1, 5, {},
     { AGH(35, 1, aK1);
       asm volatile("s_waitcnt vmcnt(8)" ::: "memory"); });   // STG(35) drained
  // tile 35 (slot s2): final, no trailing sync
  PH(s2, 0, aK0, 0, {}, {});
  PH(s2, 0, aK0, 5, {}, {});
  PH(s2, 1, aK1, 0, {}, {});
  {
    BBR(s2, 1, 5);
    CL(aK1, 5);
  }

  // epilogue: D col(px)=l&15, row(co)=(l>>4)*4+r; wave covers co [wv*64, wv*64+64)
#pragma unroll
  for (int j = 0; j < 4; ++j) {
    int cobase = wv * 64 + j * 16 + hi4 * 4;
    const float4 bv = *(const float4*)(bias + cobase);
    float* op = out + (((size_t)n * CO + cobase) * Hh + h) * Ww;
#pragma unroll
    for (int ni = 0; ni < 10; ++ni) {
      int w = ni * 16 + lc;
      f32x4 v = acc[j][ni];
      op[w]                   = v[0] + bv.x;
      op[(size_t)HWp + w]     = v[1] + bv.y;
      op[(size_t)2 * HWp + w] = v[2] + bv.z;
      op[(size_t)3 * HWp + w] = v[3] + bv.w;
    }
  }
}

extern "C" void kernel_launch(void* const* d_in, const int* in_sizes, int n_in,
                              void* d_out, int out_size, void* d_ws, size_t ws_size,
                              hipStream_t stream) {
  const int* mask = (const int*)d_in[0];
  const float* ori = (const float*)d_in[1];
  const float* weight = (const float*)d_in[2];
  const float* bias = (const float*)d_in[3];
  float* out = (float*)d_out;

  unsigned short* xp = (unsigned short*)d_ws;          // padded NHWC bf16, 107.5 MB
  unsigned short* w3 = xp + XPAD_ELEMS;                // 1.2 MB granule-ordered weights

  prep_all<<<NBORD + NPW + NPX, 256, 0, stream>>>(ori, mask, weight, xp, w3);
  sconv_gemm<<<1280, 256, 0, stream>>>(xp, w3, bias, out);
}